// Round 5
// baseline (469.200 us; speedup 1.0000x reference)
//
#include <hip/hip_runtime.h>
#include <math.h>

// Problem constants: N=8192 rows, T=1024 trials, K=10 options
#define T_TRIALS 1024
#define KOPT     10
#define RPW      6                   // rows per wave (6*10 = 60 of 64 lanes)
#define TI       16                  // trials per LDS tile
#define NTILES   (T_TRIALS / TI)     // 64
#define NPAIRS   (NTILES / 2)        // 32 tile-pairs
#define LSTRIDE  180                 // 160 + 20 pad: 180%32=20 -> max 2-way bank aliasing (free)
#define BLOCK    64                  // one wave per block -> no s_barrier anywhere

typedef int   v4i __attribute__((ext_vector_type(4)));
typedef float v4f __attribute__((ext_vector_type(4)));

__device__ __forceinline__ float sigmoidf_(float x) { return 1.0f / (1.0f + expf(-x)); }

// One RW update for the option-k chain (branchless; exact f32 reference arithmetic).
#define STEP(ct, rt)                                              \
    {                                                             \
        float pe = ((rt) == (rt)) ? ((rt) - v) : 0.0f;            \
        float lr = (pe >= 0.0f) ? ap : am;                        \
        float vn = fmaf(lr, pe, v);                               \
        v = ((ct) == k) ? vn : v;                                 \
    }

// Single-pass, barrier-free. Wave owns 6 rows x 10 options; thread (u,k) scans
// all 1024 trials of its chain in a register. Tiles are processed in PAIRS with
// the next pair's inputs prefetched (depth-2: ~2 tiles of compute slack covers
// ~900cyc HBM latency at 1.3 waves/SIMD). Pre-update values stage in
// wave-private LDS (no s_barrier needed), then stream out as nontemporal float4.
__global__ __launch_bounds__(BLOCK) void rw_fused(
    const int* __restrict__ choices, const float* __restrict__ rewards,
    const float* __restrict__ apP, const float* __restrict__ amP,
    const float* __restrict__ ivP, float* __restrict__ out, int N)
{
    // 7 row-slots: slot 6 is a dummy landing zone for the 4 idle lanes.
    __shared__ float lds[2][(RPW + 1) * LSTRIDE];   // 2*7*180*4 = 10080 B

    const int j = threadIdx.x;        // 0..63
    const int u = j / KOPT;           // 0..6 (u==6 -> dummy chain on lanes 60..63)
    const int k = j - u * KOPT;       // 0..9

    int row = blockIdx.x * RPW + (u < RPW ? u : 0);
    if (row >= N) row = N - 1;        // clamp (tail block / dummy lanes)

    const float ap = sigmoidf_(apP[0]);
    const float am = sigmoidf_(amP[0]);
    float v = 100.0f * tanhf(ivP[0]);

    const v4i* c4 = (const v4i*)(choices + (size_t)row * T_TRIALS);
    const v4f* r4 = (const v4f*)(rewards + (size_t)row * T_TRIALS);

    float* Lw[2] = { &lds[0][u * LSTRIDE + k], &lds[1][u * LSTRIDE + k] };

    // Store assignment: 6 rows x 40 float4 = 240 vectors, 64 lanes x 4 slots.
    int    s_off[4];
    float* s_dst[4];
    bool   s_ok[4];
#pragma unroll
    for (int w = 0; w < 4; ++w) {
        int idx = w * BLOCK + j;              // 0..255
        int uu  = idx / 40;                   // 0..6
        int f4  = idx - uu * 40;              // 0..39
        s_off[w] = uu * LSTRIDE + f4 * 4;
        int gu   = blockIdx.x * RPW + uu;
        s_ok[w]  = (uu < RPW) && (gu < N);
        if (gu >= N) gu = N - 1;
        s_dst[w] = out + (size_t)gu * T_TRIALS * KOPT + (size_t)f4 * 4;
    }

    // Register pipeline: current pair (8 x dwordx4 each) + next pair.
    v4i ca[8]; v4f ra[8];
    v4i cn[8]; v4f rn[8];
#pragma unroll
    for (int i = 0; i < 8; ++i) {
        ca[i] = __builtin_nontemporal_load(c4 + i);
        ra[i] = __builtin_nontemporal_load(r4 + i);
    }

    for (int p = 0; p < NPAIRS; ++p) {
        // Prefetch the next pair (wraps harmlessly on the last iteration).
        int nx = ((p + 1) & (NPAIRS - 1)) * 8;
#pragma unroll
        for (int i = 0; i < 8; ++i) {
            cn[i] = __builtin_nontemporal_load(c4 + nx + i);
            rn[i] = __builtin_nontemporal_load(r4 + nx + i);
        }

        // Two tiles: half h uses ca[4h..4h+3], LDS buffer h.
#pragma unroll
        for (int h = 0; h < 2; ++h) {
            float* L = Lw[h];
#pragma unroll
            for (int t = 0; t < 4; ++t) {
                v4i q = ca[h * 4 + t];
                v4f w = ra[h * 4 + t];
#pragma unroll
                for (int e = 0; e < 4; ++e) {
                    L[(t * 4 + e) * KOPT] = v;   // emit value BEFORE update
                    int   ct = q[e];
                    float rt = w[e];
                    STEP(ct, rt)
                }
            }

            // Wave-private transpose: per-wave LDS ops are in-order; only pin
            // compiler ordering (no vmcnt/lgkmcnt drain, no s_barrier).
            __builtin_amdgcn_wave_barrier();

            const float* Ls = &lds[h][0];
#pragma unroll
            for (int w = 0; w < 4; ++w) {
                v4f val = *(const v4f*)(Ls + s_off[w]);
                if (s_ok[w]) __builtin_nontemporal_store(val, (v4f*)s_dst[w]);
                s_dst[w] += TI * KOPT;        // advance 160 floats to next tile
            }

            __builtin_amdgcn_wave_barrier();  // next tile's LDS writes stay after reads
        }

#pragma unroll
        for (int i = 0; i < 8; ++i) { ca[i] = cn[i]; ra[i] = rn[i]; }
    }
}

extern "C" void kernel_launch(void* const* d_in, const int* in_sizes, int n_in,
                              void* d_out, int out_size, void* d_ws, size_t ws_size,
                              hipStream_t stream)
{
    const int*   choices = (const int*)  d_in[0];
    const float* rewards = (const float*)d_in[1];
    const float* ap      = (const float*)d_in[2];
    const float* am      = (const float*)d_in[3];
    const float* iv      = (const float*)d_in[4];
    float* out = (float*)d_out;

    int N    = in_sizes[0] / T_TRIALS;        // 8192
    int grid = (N + RPW - 1) / RPW;           // 1366 one-wave blocks

    rw_fused<<<grid, BLOCK, 0, stream>>>(choices, rewards, ap, am, iv, out, N);
}